// Round 9
// baseline (1589.852 us; speedup 1.0000x reference)
//
#include <hip/hip_runtime.h>

#define N_NODES 32768
#define M_EDGES 8192
#define IN_DIM  256
#define OUT_F   64

#define SCAN_ROWS 16                  // rows per scan block
#define NBLK   (N_NODES / SCAN_ROWS)  // 2048 scan blocks
#define RBCAP  192                    // per-row nz cap (mean 82, +12 sigma)
#define COLCAP 512                    // per-edge node cap (mean 328, +10 sigma)

__device__ __forceinline__ unsigned short f2bf(float x) {   // RNE f32->bf16
    unsigned u = __float_as_uint(x);
    u += 0x7FFFu + ((u >> 16) & 1u);
    return (unsigned short)(u >> 16);
}
__device__ __forceinline__ float bf2f(unsigned short h) {
    return __uint_as_float((unsigned)h << 16);
}

// ---------------------------------------------------------------------------
// Pass 1 (fused): the single full H read (1.07 GB), branch-free bitmask scan.
// Per-row epilogue emits CSR indices, CSC scatter, Dv, rowlen. (identical R8)
// ---------------------------------------------------------------------------
__global__ __launch_bounds__(256) void k_scan(const float* __restrict__ H,
                                              const float* __restrict__ w,
                                              unsigned short* __restrict__ rowidx,
                                              unsigned* __restrict__ rowlen,
                                              unsigned short* __restrict__ cscidx,
                                              unsigned* __restrict__ cscfill,
                                              float* __restrict__ Dv_raw) {
    int tid  = threadIdx.x;
    int lane = tid & 63;
    int wid  = tid >> 6;
    int row0 = blockIdx.x * SCAN_ROWS;

    for (int rr = wid; rr < SCAN_ROWS; rr += 4) {
        int n = row0 + rr;
        const float4* Hrow = (const float4*)(H + (size_t)n * M_EDGES);
        unsigned short* out_r = rowidx + (size_t)n * RBCAP;

        unsigned mreg[4];
        #pragma unroll
        for (int ob = 0; ob < 4; ++ob) {       // 4 outer blocks of 512 float4s
            int jb = ob * 512;
            float4 h0 = Hrow[jb + lane];
            float4 h1 = Hrow[jb + 64  + lane];
            float4 h2 = Hrow[jb + 128 + lane];
            float4 h3 = Hrow[jb + 192 + lane];
            float4 h4 = Hrow[jb + 256 + lane];
            float4 h5 = Hrow[jb + 320 + lane];
            float4 h6 = Hrow[jb + 384 + lane];
            float4 h7 = Hrow[jb + 448 + lane];
            unsigned mk = 0;
            #define PK(hv, g)                                                  \
            {                                                                  \
                unsigned b = (unsigned)(hv.x != 0.f)                           \
                           | ((unsigned)(hv.y != 0.f) << 1)                    \
                           | ((unsigned)(hv.z != 0.f) << 2)                    \
                           | ((unsigned)(hv.w != 0.f) << 3);                   \
                mk |= b << (4 * (g));                                          \
            }
            PK(h0, 0) PK(h1, 1) PK(h2, 2) PK(h3, 3)
            PK(h4, 4) PK(h5, 5) PK(h6, 6) PK(h7, 7)
            #undef PK
            mreg[ob] = mk;
        }

        unsigned cnt = (unsigned)(__popc(mreg[0]) + __popc(mreg[1])
                                + __popc(mreg[2]) + __popc(mreg[3]));
        unsigned incl = cnt;
        #pragma unroll
        for (int off = 1; off < 64; off <<= 1) {
            unsigned v = (unsigned)__shfl_up((int)incl, off, 64);
            if (lane >= off) incl += v;
        }
        unsigned pos = incl - cnt;
        unsigned total = (unsigned)__shfl((int)incl, 63, 64);

        float dv = 0.f;
        #pragma unroll
        for (int r = 0; r < 4; ++r) {
            unsigned mm = mreg[r];
            while (mm) {
                int p = __ffs(mm) - 1;
                int g = p >> 2;
                int c4 = p & 3;
                int m_idx = r * 2048 + g * 256 + (lane << 2) + c4;
                if (pos < RBCAP) out_r[pos] = (unsigned short)m_idx;
                ++pos;
                dv += w[m_idx];
                unsigned fp = atomicAdd(&cscfill[m_idx], 1u);
                if (fp < (unsigned)COLCAP)
                    cscidx[(size_t)m_idx * COLCAP + fp] = (unsigned short)n;
                mm &= mm - 1;
            }
        }
        for (int off = 32; off; off >>= 1) dv += __shfl_down(dv, off, 64);
        if (lane == 0) Dv_raw[n] = dv;
        if (lane == 63)
            rowlen[n] = (total < (unsigned)RBCAP) ? total : (unsigned)RBCAP;
    }
}

// ---------------------------------------------------------------------------
// Pass 2: y2[n,k] = rsqrt(max(Dv[n],1e-6)) * (x[n,:] @ W[:,k] + b[k]) -> bf16
// ---------------------------------------------------------------------------
__global__ __launch_bounds__(256) void k_lin(const float* __restrict__ x,
                                             const float* __restrict__ Wl,
                                             const float* __restrict__ b,
                                             const float* __restrict__ Dv_raw,
                                             unsigned short* __restrict__ y2b) {
    __shared__ float x_s[16 * IN_DIM];   // 16 KB
    int tid = threadIdx.x;
    int n0 = blockIdx.x * 16;
    for (int i = tid; i < 16 * IN_DIM; i += 256)
        x_s[i] = x[(size_t)n0 * IN_DIM + i];
    __syncthreads();
    int k = tid & 63;
    int rbase = tid >> 6;
    for (int pass = 0; pass < 4; ++pass) {
        int r = pass * 4 + rbase;
        float acc = b[k];
        const float* xr = x_s + r * IN_DIM;
        #pragma unroll 8
        for (int i = 0; i < IN_DIM; ++i)
            acc = fmaf(xr[i], Wl[i * OUT_F + k], acc);
        float dvis = rsqrtf(fmaxf(Dv_raw[n0 + r], 1e-6f));
        y2b[(size_t)(n0 + r) * OUT_F + k] = f2bf(acc * dvis);
    }
}

// Quad-row bf16 gather segment: lane L (g=L/16, c=L%16) loads ushort4 (4 bf16)
// of row idx[4q+g] -> 4 rows per 512 B load instruction; validity masked.
#define SEGQ(vi, base, cnt, src, ax, ay, az, aw, g, c, lane)                   \
if ((base) < (cnt)) {                                                          \
    unsigned rem = (cnt) - (base); if (rem > 64u) rem = 64u;                   \
    unsigned nq = (rem + 3u) >> 2;                                             \
    _Pragma("unroll 4")                                                        \
    for (unsigned qq = 0; qq < nq; ++qq) {                                     \
        int nidx = __shfl(vi, (int)(4u * qq) + (g), 64);                       \
        const ushort4* srcp = (const ushort4*)((src) + (size_t)nidx * OUT_F);  \
        ushort4 v = srcp[c];                                                   \
        bool ok = (4u * qq + (unsigned)(g)) < rem;                             \
        ax += ok ? bf2f(v.x) : 0.f;                                            \
        ay += ok ? bf2f(v.y) : 0.f;                                            \
        az += ok ? bf2f(v.z) : 0.f;                                            \
        aw += ok ? bf2f(v.w) : 0.f;                                            \
    }                                                                          \
}

// ---------------------------------------------------------------------------
// Pass 3: t'[m,:] = (w[m]/max(De[m],1)) * sum_{n in edge m} y2[n,:]  (bf16 io)
// ---------------------------------------------------------------------------
__global__ __launch_bounds__(256) void k_edge(const unsigned short* __restrict__ cscidx,
                                              const unsigned* __restrict__ cscfill,
                                              const float* __restrict__ w,
                                              const unsigned short* __restrict__ y2b,
                                              unsigned short* __restrict__ tb) {
    int lane = threadIdx.x & 63;
    int wid  = threadIdx.x >> 6;
    int m = blockIdx.x * 4 + wid;
    unsigned de = cscfill[m];
    unsigned cnt = (de < (unsigned)COLCAP) ? de : (unsigned)COLCAP;
    const unsigned short* cp = cscidx + (size_t)m * COLCAP;
    int g = lane >> 4;
    int c = lane & 15;
    int v0 = cp[lane];         int v1 = cp[64  + lane];
    int v2 = cp[128 + lane];   int v3 = cp[192 + lane];
    int v4 = cp[256 + lane];   int v5 = cp[320 + lane];
    int v6 = cp[384 + lane];   int v7 = cp[448 + lane];
    float ax = 0.f, ay = 0.f, az = 0.f, aw = 0.f;
    SEGQ(v0,   0u, cnt, y2b, ax, ay, az, aw, g, c, lane)
    SEGQ(v1,  64u, cnt, y2b, ax, ay, az, aw, g, c, lane)
    SEGQ(v2, 128u, cnt, y2b, ax, ay, az, aw, g, c, lane)
    SEGQ(v3, 192u, cnt, y2b, ax, ay, az, aw, g, c, lane)
    SEGQ(v4, 256u, cnt, y2b, ax, ay, az, aw, g, c, lane)
    SEGQ(v5, 320u, cnt, y2b, ax, ay, az, aw, g, c, lane)
    SEGQ(v6, 384u, cnt, y2b, ax, ay, az, aw, g, c, lane)
    SEGQ(v7, 448u, cnt, y2b, ax, ay, az, aw, g, c, lane)
    ax += __shfl_xor(ax, 16, 64); ax += __shfl_xor(ax, 32, 64);
    ay += __shfl_xor(ay, 16, 64); ay += __shfl_xor(ay, 32, 64);
    az += __shfl_xor(az, 16, 64); az += __shfl_xor(az, 32, 64);
    aw += __shfl_xor(aw, 16, 64); aw += __shfl_xor(aw, 32, 64);
    if (g == 0) {
        float sc = w[m] / fmaxf((float)de, 1.0f);
        ushort4 r4 = { f2bf(ax * sc), f2bf(ay * sc), f2bf(az * sc), f2bf(aw * sc) };
        ((ushort4*)(tb + (size_t)m * OUT_F))[c] = r4;
    }
}

// ---------------------------------------------------------------------------
// Pass 4: out[n,:] = dvis[n] * sum_{m in row n} t'[m,:]  (bf16 gather, f32 out)
// ---------------------------------------------------------------------------
__global__ __launch_bounds__(256) void k_out(const unsigned short* __restrict__ rowidx,
                                             const unsigned* __restrict__ rowlen,
                                             const unsigned short* __restrict__ tb,
                                             const float* __restrict__ Dv_raw,
                                             float* __restrict__ out) {
    int lane = threadIdx.x & 63;
    int wid  = threadIdx.x >> 6;
    int n = blockIdx.x * 4 + wid;
    unsigned cnt = rowlen[n];
    const unsigned short* rp = rowidx + (size_t)n * RBCAP;
    int g = lane >> 4;
    int c = lane & 15;
    int v0 = rp[lane];
    int v1 = rp[64  + lane];
    int v2 = rp[128 + lane];
    float ax = 0.f, ay = 0.f, az = 0.f, aw = 0.f;
    SEGQ(v0,   0u, cnt, tb, ax, ay, az, aw, g, c, lane)
    SEGQ(v1,  64u, cnt, tb, ax, ay, az, aw, g, c, lane)
    SEGQ(v2, 128u, cnt, tb, ax, ay, az, aw, g, c, lane)
    ax += __shfl_xor(ax, 16, 64); ax += __shfl_xor(ax, 32, 64);
    ay += __shfl_xor(ay, 16, 64); ay += __shfl_xor(ay, 32, 64);
    az += __shfl_xor(az, 16, 64); az += __shfl_xor(az, 32, 64);
    aw += __shfl_xor(aw, 16, 64); aw += __shfl_xor(aw, 32, 64);
    if (g == 0) {
        float dvis = rsqrtf(fmaxf(Dv_raw[n], 1e-6f));
        float4 r4 = { ax * dvis, ay * dvis, az * dvis, aw * dvis };
        ((float4*)(out + (size_t)n * OUT_F))[c] = r4;
    }
}

// ---------------------------------------------------------------------------
extern "C" void kernel_launch(void* const* d_in, const int* in_sizes, int n_in,
                              void* d_out, int out_size, void* d_ws, size_t ws_size,
                              hipStream_t stream) {
    const float* x  = (const float*)d_in[0];
    const float* H  = (const float*)d_in[1];
    const float* w  = (const float*)d_in[2];
    const float* Wl = (const float*)d_in[3];
    const float* bl = (const float*)d_in[4];
    float* out = (float*)d_out;

    // workspace (~25 MB):
    // y2b[N*64] ushort | tb[M*64] ushort | Dv[N] | rowlen[N] | cscfill[M]
    // | rowidx[N*RBCAP] ushort | cscidx[M*COLCAP] ushort
    unsigned short* y2b = (unsigned short*)d_ws;
    unsigned short* tb  = y2b + (size_t)N_NODES * OUT_F;
    float*    Dv_raw    = (float*)(tb + (size_t)M_EDGES * OUT_F);
    unsigned* rowlen    = (unsigned*)(Dv_raw + N_NODES);
    unsigned* cscfill   = rowlen + N_NODES;
    unsigned short* rowidx = (unsigned short*)(cscfill + M_EDGES);
    unsigned short* cscidx = rowidx + (size_t)N_NODES * RBCAP;

    hipMemsetAsync(cscfill, 0, M_EDGES * sizeof(unsigned), stream);

    k_scan<<<dim3(NBLK),         dim3(256), 0, stream>>>(H, w, rowidx, rowlen, cscidx, cscfill, Dv_raw);
    k_lin <<<dim3(N_NODES / 16), dim3(256), 0, stream>>>(x, Wl, bl, Dv_raw, y2b);
    k_edge<<<dim3(M_EDGES / 4),  dim3(256), 0, stream>>>(cscidx, cscfill, w, y2b, tb);
    k_out <<<dim3(N_NODES / 4),  dim3(256), 0, stream>>>(rowidx, rowlen, tb, Dv_raw, out);
}

// Round 10
// 1535.457 us; speedup vs baseline: 1.0354x; 1.0354x over previous
//
#include <hip/hip_runtime.h>

#define N_NODES 32768
#define M_EDGES 8192
#define IN_DIM  256
#define OUT_F   64

#define SCAN_ROWS 16                  // rows per scan block
#define NBLK   (N_NODES / SCAN_ROWS)  // 2048 scan blocks
#define RBCAP  192                    // per-row nz cap (mean 82, +12 sigma)
#define COLCAP 512                    // per-edge node cap (mean 328, +10 sigma)

// ---------------------------------------------------------------------------
// Pass 1 (fused): the single full H read (1.07 GB), branch-free bitmask scan.
// Per-row epilogue emits: CSR indices, CSC scatter (returning atomic + 2B
// store, lane-parallel, hidden under next row's loads), Dv (w-gather), rowlen.
// ---------------------------------------------------------------------------
__global__ __launch_bounds__(256) void k_scan(const float* __restrict__ H,
                                              const float* __restrict__ w,
                                              unsigned short* __restrict__ rowidx,
                                              unsigned* __restrict__ rowlen,
                                              unsigned short* __restrict__ cscidx,
                                              unsigned* __restrict__ cscfill,
                                              float* __restrict__ Dv_raw) {
    int tid  = threadIdx.x;
    int lane = tid & 63;
    int wid  = tid >> 6;
    int row0 = blockIdx.x * SCAN_ROWS;

    for (int rr = wid; rr < SCAN_ROWS; rr += 4) {
        int n = row0 + rr;
        const float4* Hrow = (const float4*)(H + (size_t)n * M_EDGES);
        unsigned short* out_r = rowidx + (size_t)n * RBCAP;

        unsigned mreg[4];
        #pragma unroll
        for (int ob = 0; ob < 4; ++ob) {       // 4 outer blocks of 512 float4s
            int jb = ob * 512;
            float4 h0 = Hrow[jb + lane];
            float4 h1 = Hrow[jb + 64  + lane];
            float4 h2 = Hrow[jb + 128 + lane];
            float4 h3 = Hrow[jb + 192 + lane];
            float4 h4 = Hrow[jb + 256 + lane];
            float4 h5 = Hrow[jb + 320 + lane];
            float4 h6 = Hrow[jb + 384 + lane];
            float4 h7 = Hrow[jb + 448 + lane];
            unsigned mk = 0;
            #define PK(hv, g)                                                  \
            {                                                                  \
                unsigned b = (unsigned)(hv.x != 0.f)                           \
                           | ((unsigned)(hv.y != 0.f) << 1)                    \
                           | ((unsigned)(hv.z != 0.f) << 2)                    \
                           | ((unsigned)(hv.w != 0.f) << 3);                   \
                mk |= b << (4 * (g));                                          \
            }
            PK(h0, 0) PK(h1, 1) PK(h2, 2) PK(h3, 3)
            PK(h4, 4) PK(h5, 5) PK(h6, 6) PK(h7, 7)
            #undef PK
            mreg[ob] = mk;
        }

        // per-lane count + wave exclusive prefix (6-step shfl scan)
        unsigned cnt = (unsigned)(__popc(mreg[0]) + __popc(mreg[1])
                                + __popc(mreg[2]) + __popc(mreg[3]));
        unsigned incl = cnt;
        #pragma unroll
        for (int off = 1; off < 64; off <<= 1) {
            unsigned v = (unsigned)__shfl_up((int)incl, off, 64);
            if (lane >= off) incl += v;
        }
        unsigned pos = incl - cnt;                       // exclusive prefix
        unsigned total = (unsigned)__shfl((int)incl, 63, 64);

        // emit: bit p of mreg[r] -> m = r*2048 + (p>>2)*256 + lane*4 + (p&3)
        float dv = 0.f;
        #pragma unroll
        for (int r = 0; r < 4; ++r) {
            unsigned mm = mreg[r];
            while (mm) {
                int p = __ffs(mm) - 1;
                int g = p >> 2;
                int c4 = p & 3;
                int m_idx = r * 2048 + g * 256 + (lane << 2) + c4;
                if (pos < RBCAP) out_r[pos] = (unsigned short)m_idx;
                ++pos;
                dv += w[m_idx];
                unsigned fp = atomicAdd(&cscfill[m_idx], 1u);
                if (fp < (unsigned)COLCAP)
                    cscidx[(size_t)m_idx * COLCAP + fp] = (unsigned short)n;
                mm &= mm - 1;
            }
        }
        for (int off = 32; off; off >>= 1) dv += __shfl_down(dv, off, 64);
        if (lane == 0) Dv_raw[n] = dv;
        if (lane == 63)
            rowlen[n] = (total < (unsigned)RBCAP) ? total : (unsigned)RBCAP;
    }
}

// ---------------------------------------------------------------------------
// Pass 2: y2[n,k] = rsqrt(max(Dv[n],1e-6)) * (x[n,:] @ W[:,k] + b[k])
// ---------------------------------------------------------------------------
__global__ __launch_bounds__(256) void k_lin(const float* __restrict__ x,
                                             const float* __restrict__ Wl,
                                             const float* __restrict__ b,
                                             const float* __restrict__ Dv_raw,
                                             float* __restrict__ y2) {
    __shared__ float x_s[16 * IN_DIM];   // 16 KB
    int tid = threadIdx.x;
    int n0 = blockIdx.x * 16;
    for (int i = tid; i < 16 * IN_DIM; i += 256)
        x_s[i] = x[(size_t)n0 * IN_DIM + i];
    __syncthreads();
    int k = tid & 63;
    int rbase = tid >> 6;
    for (int pass = 0; pass < 4; ++pass) {
        int r = pass * 4 + rbase;
        float acc = b[k];
        const float* xr = x_s + r * IN_DIM;
        #pragma unroll 8
        for (int i = 0; i < IN_DIM; ++i)
            acc = fmaf(xr[i], Wl[i * OUT_F + k], acc);
        float dvis = rsqrtf(fmaxf(Dv_raw[n0 + r], 1e-6f));
        y2[(size_t)(n0 + r) * OUT_F + k] = acc * dvis;
    }
}

// Quad-row gather segment: lane L (g=L/16, c=L%16) loads float4 of row
// idx[4q+g] -> 4 rows per 1 KB load instruction; per-entry validity masked.
#define SEGQ(vi, base, cnt, src, ax, ay, az, aw, g, c, lane)                   \
if ((base) < (cnt)) {                                                          \
    unsigned rem = (cnt) - (base); if (rem > 64u) rem = 64u;                   \
    unsigned nq = (rem + 3u) >> 2;                                             \
    _Pragma("unroll 4")                                                        \
    for (unsigned qq = 0; qq < nq; ++qq) {                                     \
        int nidx = __shfl(vi, (int)(4u * qq) + (g), 64);                       \
        const float4* srcp = (const float4*)((src) + (size_t)nidx * OUT_F);    \
        float4 v = srcp[c];                                                    \
        bool ok = (4u * qq + (unsigned)(g)) < rem;                             \
        ax += ok ? v.x : 0.f;                                                  \
        ay += ok ? v.y : 0.f;                                                  \
        az += ok ? v.z : 0.f;                                                  \
        aw += ok ? v.w : 0.f;                                                  \
    }                                                                          \
}

// ---------------------------------------------------------------------------
// Pass 3: t'[m,:] = (w[m]/max(De[m],1)) * sum_{n in edge m} y2[n,:]
// One wave per edge; quad-row float4 gathers; 2-shfl cross-group reduce;
// 16-lane dwordx4 store. No atomics.
// ---------------------------------------------------------------------------
__global__ __launch_bounds__(256) void k_edge(const unsigned short* __restrict__ cscidx,
                                              const unsigned* __restrict__ cscfill,
                                              const float* __restrict__ w,
                                              const float* __restrict__ y2,
                                              float* __restrict__ t) {
    int lane = threadIdx.x & 63;
    int wid  = threadIdx.x >> 6;
    int m = blockIdx.x * 4 + wid;
    unsigned de = cscfill[m];
    unsigned cnt = (de < (unsigned)COLCAP) ? de : (unsigned)COLCAP;
    const unsigned short* cp = cscidx + (size_t)m * COLCAP;
    int g = lane >> 4;
    int c = lane & 15;
    int v0 = cp[lane];         int v1 = cp[64  + lane];
    int v2 = cp[128 + lane];   int v3 = cp[192 + lane];
    int v4 = cp[256 + lane];   int v5 = cp[320 + lane];
    int v6 = cp[384 + lane];   int v7 = cp[448 + lane];
    float ax = 0.f, ay = 0.f, az = 0.f, aw = 0.f;
    SEGQ(v0,   0u, cnt, y2, ax, ay, az, aw, g, c, lane)
    SEGQ(v1,  64u, cnt, y2, ax, ay, az, aw, g, c, lane)
    SEGQ(v2, 128u, cnt, y2, ax, ay, az, aw, g, c, lane)
    SEGQ(v3, 192u, cnt, y2, ax, ay, az, aw, g, c, lane)
    SEGQ(v4, 256u, cnt, y2, ax, ay, az, aw, g, c, lane)
    SEGQ(v5, 320u, cnt, y2, ax, ay, az, aw, g, c, lane)
    SEGQ(v6, 384u, cnt, y2, ax, ay, az, aw, g, c, lane)
    SEGQ(v7, 448u, cnt, y2, ax, ay, az, aw, g, c, lane)
    ax += __shfl_xor(ax, 16, 64); ax += __shfl_xor(ax, 32, 64);
    ay += __shfl_xor(ay, 16, 64); ay += __shfl_xor(ay, 32, 64);
    az += __shfl_xor(az, 16, 64); az += __shfl_xor(az, 32, 64);
    aw += __shfl_xor(aw, 16, 64); aw += __shfl_xor(aw, 32, 64);
    if (g == 0) {
        float sc = w[m] / fmaxf((float)de, 1.0f);
        float4 r4 = { ax * sc, ay * sc, az * sc, aw * sc };
        ((float4*)(t + (size_t)m * OUT_F))[c] = r4;
    }
}

// ---------------------------------------------------------------------------
// Pass 4: out[n,:] = dvis[n] * sum_{m in row n} t'[m,:].  Same quad-gather.
// ---------------------------------------------------------------------------
__global__ __launch_bounds__(256) void k_out(const unsigned short* __restrict__ rowidx,
                                             const unsigned* __restrict__ rowlen,
                                             const float* __restrict__ t,
                                             const float* __restrict__ Dv_raw,
                                             float* __restrict__ out) {
    int lane = threadIdx.x & 63;
    int wid  = threadIdx.x >> 6;
    int n = blockIdx.x * 4 + wid;
    unsigned cnt = rowlen[n];
    const unsigned short* rp = rowidx + (size_t)n * RBCAP;
    int g = lane >> 4;
    int c = lane & 15;
    int v0 = rp[lane];
    int v1 = rp[64  + lane];
    int v2 = rp[128 + lane];
    float ax = 0.f, ay = 0.f, az = 0.f, aw = 0.f;
    SEGQ(v0,   0u, cnt, t, ax, ay, az, aw, g, c, lane)
    SEGQ(v1,  64u, cnt, t, ax, ay, az, aw, g, c, lane)
    SEGQ(v2, 128u, cnt, t, ax, ay, az, aw, g, c, lane)
    ax += __shfl_xor(ax, 16, 64); ax += __shfl_xor(ax, 32, 64);
    ay += __shfl_xor(ay, 16, 64); ay += __shfl_xor(ay, 32, 64);
    az += __shfl_xor(az, 16, 64); az += __shfl_xor(az, 32, 64);
    aw += __shfl_xor(aw, 16, 64); aw += __shfl_xor(aw, 32, 64);
    if (g == 0) {
        float dvis = rsqrtf(fmaxf(Dv_raw[n], 1e-6f));
        float4 r4 = { ax * dvis, ay * dvis, az * dvis, aw * dvis };
        ((float4*)(out + (size_t)n * OUT_F))[c] = r4;
    }
}

// ---------------------------------------------------------------------------
extern "C" void kernel_launch(void* const* d_in, const int* in_sizes, int n_in,
                              void* d_out, int out_size, void* d_ws, size_t ws_size,
                              hipStream_t stream) {
    const float* x  = (const float*)d_in[0];
    const float* H  = (const float*)d_in[1];
    const float* w  = (const float*)d_in[2];
    const float* Wl = (const float*)d_in[3];
    const float* bl = (const float*)d_in[4];
    float* out = (float*)d_out;

    // workspace (~31.7 MB):
    // y2[N*64] | t[M*64] | Dv[N] | rowlen[N] | cscfill[M]
    // | rowidx[N*RBCAP] ushort | cscidx[M*COLCAP] ushort
    float*    y2      = (float*)d_ws;
    float*    t       = y2 + (size_t)N_NODES * OUT_F;
    float*    Dv_raw  = t + (size_t)M_EDGES * OUT_F;
    unsigned* rowlen  = (unsigned*)(Dv_raw + N_NODES);
    unsigned* cscfill = rowlen + N_NODES;
    unsigned short* rowidx = (unsigned short*)(cscfill + M_EDGES);
    unsigned short* cscidx = rowidx + (size_t)N_NODES * RBCAP;

    hipMemsetAsync(cscfill, 0, M_EDGES * sizeof(unsigned), stream);

    k_scan<<<dim3(NBLK),         dim3(256), 0, stream>>>(H, w, rowidx, rowlen, cscidx, cscfill, Dv_raw);
    k_lin <<<dim3(N_NODES / 16), dim3(256), 0, stream>>>(x, Wl, bl, Dv_raw, y2);
    k_edge<<<dim3(M_EDGES / 4),  dim3(256), 0, stream>>>(cscidx, cscfill, w, y2, t);
    k_out <<<dim3(N_NODES / 4),  dim3(256), 0, stream>>>(rowidx, rowlen, t, Dv_raw, out);
}